// Round 4
// baseline (240.394 us; speedup 1.0000x reference)
//
#include <hip/hip_runtime.h>
#include <hip/hip_fp16.h>

// dot_attention: out[b,n] = exp(diag*s - lse_n), s = (D/2)^-0.5 = 1/16.
// B=4, N=4096, D=512. Inputs fp32, output fp32.
// No fp32 MFMA on CDNA4 -> fp16 convert + mfma_f32_16x16x32_f16 (absmax ~8e-6).
//
// R4: split-source B. R3 was LDS-pipe-bound (2 MFMA per b128 read; 8 waves/CU
// demand ~3-4K cyc/round on LDS vs 2.5K on MFMA). Now nf=0 B-half comes from a
// 16-row LDS tile, nf=1 B-half is loaded straight from L2-resident kvh into a
// 16-frag register buffer (prefetched at iter start, consumed after the nf0
// loop). LDS demand halves -> MFMA pipe becomes the bound.

typedef _Float16 f16x8 __attribute__((ext_vector_type(8)));  // MFMA A/B frag (4 VGPR)
typedef float    f32x4 __attribute__((ext_vector_type(4)));  // MFMA C/D frag

#define NB 4
#define NN 4096
#define ND 512
#define SCALE 0.0625f
#define NROWS (NB * NN)            // 16384
#define RPITCH 1040                // 1024 data + 16 pad; 260 banks ≡ 4 mod 32
#define TBYTES (16 * RPITCH)       // 16 staged rows per tile = 16640 B

__device__ __forceinline__ void gld16(const void* g, void* l) {
    __builtin_amdgcn_global_load_lds(
        (const __attribute__((address_space(1))) unsigned int*)g,
        (__attribute__((address_space(3))) unsigned int*)l, 16, 0, 0);
}

__device__ __forceinline__ f16x8 cvt8(float4 a, float4 b) {
    f16x8 r;
    r[0] = (_Float16)a.x; r[1] = (_Float16)a.y; r[2] = (_Float16)a.z; r[3] = (_Float16)a.w;
    r[4] = (_Float16)b.x; r[5] = (_Float16)b.y; r[6] = (_Float16)b.z; r[7] = (_Float16)b.w;
    return r;
}

// ---- kernel 1: kv fp32 -> fp16 copy (for MFMA B) + diag dot (fp32 exact path)
__launch_bounds__(256)
__global__ void convert_kernel(const float* __restrict__ q,
                               const float* __restrict__ kv,
                               _Float16* __restrict__ kvh,
                               float* __restrict__ diag) {
    const int row  = blockIdx.x * 4 + (threadIdx.x >> 6);
    const int lane = threadIdx.x & 63;

    const float4* kr = (const float4*)(kv + (size_t)row * ND) + lane * 2;
    const float4* qr = (const float4*)(q  + (size_t)row * ND) + lane * 2;
    float4 k0 = kr[0], k1 = kr[1];
    float4 q0 = qr[0], q1 = qr[1];

    *(f16x8*)(kvh + (size_t)row * ND + lane * 8) = cvt8(k0, k1);

    float dot = q0.x * k0.x;
    dot = fmaf(q0.y, k0.y, dot); dot = fmaf(q0.z, k0.z, dot); dot = fmaf(q0.w, k0.w, dot);
    dot = fmaf(q1.x, k1.x, dot); dot = fmaf(q1.y, k1.y, dot);
    dot = fmaf(q1.z, k1.z, dot); dot = fmaf(q1.w, k1.w, dot);

    dot += __shfl_xor(dot, 1, 64);
    dot += __shfl_xor(dot, 2, 64);
    dot += __shfl_xor(dot, 4, 64);
    dot += __shfl_xor(dot, 8, 64);
    dot += __shfl_xor(dot, 16, 64);
    dot += __shfl_xor(dot, 32, 64);
    if (lane == 0) diag[row] = dot;
}

// ---- kernel 2: per-row sum of exp(score) over a 1024-column split.
// grid (16: b*4+cs, 32: rowblock) = 512 blocks, 256 threads = 4 waves,
// 2 blocks/CU, 2 waves/SIMD. Wave: 32 q-rows (Af 128 regs, AGPR-resident),
// per iter a 32-row kv group: rows 0-15 via LDS tile (DMA-staged, dbuf),
// rows 16-31 via direct global b128 loads into a 16-frag register buffer.
__launch_bounds__(256, 2)
__global__ void lse_partial_kernel(const float* __restrict__ q,
                                   const _Float16* __restrict__ kvh,
                                   float* __restrict__ partial) {
    __shared__ char sbuf[2][TBYTES];

    const int bc = blockIdx.x;          // b*4 + cs (fastest -> 2 bc values per XCD)
    const int b  = bc >> 2;
    const int cs = bc & 3;
    const int rb = blockIdx.y;
    const int tid  = threadIdx.x;
    const int wid  = tid >> 6;
    const int lane = tid & 63;
    const int l15  = lane & 15;
    const int quad = lane >> 4;

    const int row0 = rb * 128 + wid * 32;    // wave's first q-row (in batch)

    // ---- A fragments: q fp32 -> fp16, A[row = lane&15][k = quad*8+j]
    f16x8 Af[2][16];
    #pragma unroll
    for (int m = 0; m < 2; ++m) {
        const float* qrow = q + ((size_t)(b * NN + row0 + m * 16 + l15)) * ND + quad * 8;
        #pragma unroll
        for (int k = 0; k < 16; ++k) {
            float4 u0 = *(const float4*)(qrow + k * 32);
            float4 u1 = *(const float4*)(qrow + k * 32 + 4);
            Af[m][k] = cvt8(u0, u1);
        }
    }

    float lacc[2][4];
    #pragma unroll
    for (int m = 0; m < 2; ++m)
        #pragma unroll
        for (int j = 0; j < 4; ++j)
            lacc[m][j] = 0.f;

    // nf0 B-frag LDS base: row = l15, chunk = quad
    const unsigned base0 = (unsigned)(l15 * RPITCH + quad * 16);

    const _Float16* kvbase = kvh + ((size_t)(b * NN + cs * 1024)) * ND;
    // nf1 global source: row = it*32 + 16 + l15, halfword offset kt*32 + quad*8
    const _Float16* g1base = kvbase + (size_t)(16 + l15) * ND + quad * 8;

    // stage nf0 half (16 rows) of tile `it` into sbuf[buf]: 4 rows per wave
    #define STAGE(it_, buf_)                                                 \
        do {                                                                 \
            const _Float16* gb_ = kvbase + (size_t)(it_) * 32 * ND;          \
            char* lb_ = sbuf[buf_];                                          \
            _Pragma("unroll")                                                \
            for (int p_ = 0; p_ < 4; ++p_) {                                 \
                int r_ = wid * 4 + p_;                                       \
                gld16(gb_ + (size_t)r_ * ND + lane * 8, lb_ + r_ * RPITCH);  \
            }                                                                \
        } while (0)

    STAGE(0, 0);
    int buf = 0;

    for (int it = 0; it < 32; ++it) {
        __syncthreads();                      // tile-`it` DMA drained

        // issue nf1 register loads for THIS iter (L1/L2-resident kv)
        f16x8 bn[16];
        {
            const _Float16* g1 = g1base + (size_t)it * 32 * ND;
            #pragma unroll
            for (int kt = 0; kt < 16; ++kt)
                bn[kt] = *(const f16x8*)(g1 + kt * 32);
        }

        if (it + 1 < 32) STAGE(it + 1, buf ^ 1);

        const char* lb = sbuf[buf];
        f32x4 acc[2][2];
        #pragma unroll
        for (int m = 0; m < 2; ++m)
            #pragma unroll
            for (int nf = 0; nf < 2; ++nf)
                acc[m][nf] = (f32x4){0.f, 0.f, 0.f, 0.f};

        // nf0: B from LDS (covers bn[] load latency)
        #pragma unroll
        for (int kt = 0; kt < 16; ++kt) {
            f16x8 b0 = *(const f16x8*)(lb + base0 + kt * 64);
            acc[0][0] = __builtin_amdgcn_mfma_f32_16x16x32_f16(Af[0][kt], b0, acc[0][0], 0, 0, 0);
            acc[1][0] = __builtin_amdgcn_mfma_f32_16x16x32_f16(Af[1][kt], b0, acc[1][0], 0, 0, 0);
        }
        // nf1: B from registers
        #pragma unroll
        for (int kt = 0; kt < 16; ++kt) {
            acc[0][1] = __builtin_amdgcn_mfma_f32_16x16x32_f16(Af[0][kt], bn[kt], acc[0][1], 0, 0, 0);
            acc[1][1] = __builtin_amdgcn_mfma_f32_16x16x32_f16(Af[1][kt], bn[kt], acc[1][1], 0, 0, 0);
        }

        // C/D: col = lane&15 (kv col), row = quad*4 + j (q row). Fold exp.
        #pragma unroll
        for (int m = 0; m < 2; ++m)
            #pragma unroll
            for (int nf = 0; nf < 2; ++nf)
                #pragma unroll
                for (int j = 0; j < 4; ++j)
                    lacc[m][j] += __expf(acc[m][nf][j] * SCALE);

        buf ^= 1;
    }

    // reduce over the 16 columns held across l15 lanes
    #pragma unroll
    for (int m = 0; m < 2; ++m)
        #pragma unroll
        for (int j = 0; j < 4; ++j) {
            float v = lacc[m][j];
            v += __shfl_xor(v, 1, 64);
            v += __shfl_xor(v, 2, 64);
            v += __shfl_xor(v, 4, 64);
            v += __shfl_xor(v, 8, 64);
            if (l15 == 0)
                partial[(size_t)cs * NROWS + b * NN + row0 + m * 16 + quad * 4 + j] = v;
        }
}

// ---- kernel 3: out = exp(diag*s) / sum_cs partial
__launch_bounds__(256)
__global__ void finalize_kernel(const float* __restrict__ partial,
                                const float* __restrict__ diag,
                                float* __restrict__ out) {
    const int idx = blockIdx.x * 256 + threadIdx.x;
    float l = partial[idx] + partial[NROWS + idx] +
              partial[2 * NROWS + idx] + partial[3 * NROWS + idx];
    out[idx] = __expf(diag[idx] * SCALE) / l;
}

extern "C" void kernel_launch(void* const* d_in, const int* in_sizes, int n_in,
                              void* d_out, int out_size, void* d_ws, size_t ws_size,
                              hipStream_t stream) {
    const float* q  = (const float*)d_in[0];
    const float* kv = (const float*)d_in[1];
    float* out = (float*)d_out;

    // ws layout: kvh fp16 [16MB] | partial f32[4][16384] (256KB) | diag f32[16384]
    _Float16* kvh   = (_Float16*)d_ws;
    float* partial  = (float*)((char*)d_ws + (size_t)NROWS * ND * 2);
    float* diag     = partial + 4 * NROWS;

    convert_kernel<<<NROWS / 4, 256, 0, stream>>>(q, kv, kvh, diag);
    lse_partial_kernel<<<dim3(16, 32), 256, 0, stream>>>(q, kvh, partial);
    finalize_kernel<<<NROWS / 256, 256, 0, stream>>>(partial, diag, out);
}

// Round 5
// 209.769 us; speedup vs baseline: 1.1460x; 1.1460x over previous
//
#include <hip/hip_runtime.h>
#include <hip/hip_fp16.h>

// dot_attention: out[b,n] = exp(diag*s - lse_n), s = (D/2)^-0.5 = 1/16.
// B=4, N=4096, D=512. Inputs fp32, output fp32.
// No fp32 MFMA on CDNA4 -> fp16 convert + mfma_f32_16x16x32_f16 (absmax ~8e-6).
//
// R5: fragment-packed kv. convert_kernel writes kv (fp16) in MFMA-B-frag
// order: frag(g,kt) = 1KB contiguous, byte lane*16 = lane's fragment of
// kv rows [g*16..g*16+16) x halfwords [kt*32 + quad*8). This makes BOTH
// B paths linear: LDS DMA staging (uniform-base + lane*16) and direct
// coalesced global b128 loads. Per iter: nf0 B-half from LDS (dbuf 2x16KB),
// nf1 B-half from global (L1/L2-resident, shared by all waves of a block).
// Splits B traffic across the LDS pipe and the vector path -> MFMA-bound.
// R4 lesson: direct-global B is only viable coalesced (scatter = 16 tx/inst).

typedef _Float16 f16x8 __attribute__((ext_vector_type(8)));  // MFMA A/B frag (4 VGPR)
typedef float    f32x4 __attribute__((ext_vector_type(4)));  // MFMA C/D frag

#define NB 4
#define NN 4096
#define ND 512
#define SCALE 0.0625f
#define NROWS (NB * NN)            // 16384
#define FRAG_B 1024                // bytes per packed fragment
#define GRP_B  16384               // bytes per 16-row group (16 frags)

__device__ __forceinline__ void gld16(const void* g, void* l) {
    __builtin_amdgcn_global_load_lds(
        (const __attribute__((address_space(1))) unsigned int*)g,
        (__attribute__((address_space(3))) unsigned int*)l, 16, 0, 0);
}

__device__ __forceinline__ f16x8 cvt8(float4 a, float4 b) {
    f16x8 r;
    r[0] = (_Float16)a.x; r[1] = (_Float16)a.y; r[2] = (_Float16)a.z; r[3] = (_Float16)a.w;
    r[4] = (_Float16)b.x; r[5] = (_Float16)b.y; r[6] = (_Float16)b.z; r[7] = (_Float16)b.w;
    return r;
}

__device__ __forceinline__ f16x8 cvt8s(float4 a, float4 b, float s) {
    f16x8 r;
    r[0] = (_Float16)(a.x * s); r[1] = (_Float16)(a.y * s);
    r[2] = (_Float16)(a.z * s); r[3] = (_Float16)(a.w * s);
    r[4] = (_Float16)(b.x * s); r[5] = (_Float16)(b.y * s);
    r[6] = (_Float16)(b.z * s); r[7] = (_Float16)(b.w * s);
    return r;
}

// ---- kernel 1: kv fp32 -> fp16 packed in B-frag order; + diag dot (fp32).
// One wave per 8 kv rows (half 16-row group). Reads coalesced (lane*32B of a
// row); writes 16B chunks scattered within the group's 16KB (L2-merged).
__launch_bounds__(256)
__global__ void convert_kernel(const float* __restrict__ q,
                               const float* __restrict__ kv,
                               _Float16* __restrict__ kvp,
                               float* __restrict__ diag) {
    const int w    = blockIdx.x * 4 + (threadIdx.x >> 6);  // 0..2047
    const int lane = threadIdx.x & 63;
    const int gg   = w >> 1;          // global 16-row group, 0..1023
    const int h    = w & 1;           // which 8-row half
    const int kt   = lane >> 2;
    const int quad = lane & 3;

    const int r0 = gg * 16 + h * 8;   // global row (batches contiguous)

    #pragma unroll
    for (int i = 0; i < 8; ++i) {
        const int row = r0 + i;
        const int l15 = h * 8 + i;
        const float* ks = kv + (size_t)row * ND + lane * 8;
        const float* qs = q  + (size_t)row * ND + lane * 8;
        float4 k0 = *(const float4*)ks, k1 = *(const float4*)(ks + 4);
        float4 q0 = *(const float4*)qs, q1 = *(const float4*)(qs + 4);

        // packed: ((gg*16 + kt)*64 + quad*16 + l15) * 8 halfwords
        *(f16x8*)(kvp + (((size_t)(gg * 16 + kt) * 64 + quad * 16 + l15) * 8)) =
            cvt8(k0, k1);

        float dot = q0.x * k0.x;
        dot = fmaf(q0.y, k0.y, dot); dot = fmaf(q0.z, k0.z, dot); dot = fmaf(q0.w, k0.w, dot);
        dot = fmaf(q1.x, k1.x, dot); dot = fmaf(q1.y, k1.y, dot);
        dot = fmaf(q1.z, k1.z, dot); dot = fmaf(q1.w, k1.w, dot);

        dot += __shfl_xor(dot, 1, 64);
        dot += __shfl_xor(dot, 2, 64);
        dot += __shfl_xor(dot, 4, 64);
        dot += __shfl_xor(dot, 8, 64);
        dot += __shfl_xor(dot, 16, 64);
        dot += __shfl_xor(dot, 32, 64);
        if (lane == 0) diag[row] = dot;
    }
}

// ---- kernel 2: per-row sum of exp(score) over a 1024-column split.
// grid (16: b*4+cs, 32: rowblock) = 512 blocks, 256 threads = 4 waves,
// 2 blocks/CU (2x16KB LDS dbuf), 2 waves/SIMD. Wave: 32 q-rows, A-frags
// (q * 1/16, fp16) register-resident. Per iter 32 kv rows: group g0 via
// LDS DMA tile, group g1 via coalesced global b128 into registers.
__launch_bounds__(256, 2)
__global__ void lse_partial_kernel(const float* __restrict__ q,
                                   const _Float16* __restrict__ kvp,
                                   float* __restrict__ partial) {
    __shared__ char sbuf[2][GRP_B];

    const int bc = blockIdx.x;          // b*4 + cs (fastest -> 2 bc per XCD)
    const int b  = bc >> 2;
    const int cs = bc & 3;
    const int rb = blockIdx.y;
    const int tid  = threadIdx.x;
    const int wid  = tid >> 6;
    const int lane = tid & 63;
    const int l15  = lane & 15;
    const int quad = lane >> 4;

    const int row0 = rb * 128 + wid * 32;    // wave's first q-row (in batch)

    // ---- A fragments: q fp32 -> fp16 scaled by 1/16 (exact pow2).
    f16x8 Af[2][16];
    #pragma unroll
    for (int m = 0; m < 2; ++m) {
        const float* qrow = q + ((size_t)(b * NN + row0 + m * 16 + l15)) * ND + quad * 8;
        #pragma unroll
        for (int k = 0; k < 16; ++k) {
            float4 u0 = *(const float4*)(qrow + k * 32);
            float4 u1 = *(const float4*)(qrow + k * 32 + 4);
            Af[m][k] = cvt8s(u0, u1, SCALE);
        }
    }

    float lacc[2][4];
    #pragma unroll
    for (int m = 0; m < 2; ++m)
        #pragma unroll
        for (int j = 0; j < 4; ++j)
            lacc[m][j] = 0.f;

    // packed base for this (b,cs): groups [b*256 + cs*64, +64)
    const char* pb  = (const char*)kvp + ((size_t)(b * 256 + cs * 64)) * GRP_B;
    const char* g1b = pb + GRP_B + (size_t)lane * 16;   // odd group, lane chunk
    const char* ssb = pb + (size_t)lane * 16;           // even group, lane chunk

    // stage even group of tile `it_` into sbuf[buf_]: 4 frag-DMAs per wave
    #define STAGE(it_, buf_)                                                  \
        do {                                                                  \
            const char* sp_ = ssb + (size_t)(it_) * (2 * GRP_B);              \
            char* lb_ = sbuf[buf_];                                           \
            _Pragma("unroll")                                                 \
            for (int p_ = 0; p_ < 4; ++p_) {                                  \
                int kt_ = wid * 4 + p_;                                       \
                gld16(sp_ + kt_ * FRAG_B, lb_ + kt_ * FRAG_B);                \
            }                                                                 \
        } while (0)

    STAGE(0, 0);
    int buf = 0;

    for (int it = 0; it < 32; ++it) {
        __syncthreads();                      // tile-`it` DMA drained

        // coalesced register loads of the odd group's 16 frags (L1/L2-hot)
        f16x8 bn[16];
        {
            const char* g1 = g1b + (size_t)it * (2 * GRP_B);
            #pragma unroll
            for (int kt = 0; kt < 16; ++kt)
                bn[kt] = *(const f16x8*)(g1 + kt * FRAG_B);
        }

        if (it + 1 < 32) STAGE(it + 1, buf ^ 1);

        const char* lb = sbuf[buf] + (size_t)lane * 16;
        f32x4 acc[2][2];
        #pragma unroll
        for (int m = 0; m < 2; ++m)
            #pragma unroll
            for (int nf = 0; nf < 2; ++nf)
                acc[m][nf] = (f32x4){0.f, 0.f, 0.f, 0.f};

        // nf0: B from LDS (also covers bn[] load latency)
        #pragma unroll
        for (int kt = 0; kt < 16; ++kt) {
            f16x8 b0 = *(const f16x8*)(lb + kt * FRAG_B);
            acc[0][0] = __builtin_amdgcn_mfma_f32_16x16x32_f16(Af[0][kt], b0, acc[0][0], 0, 0, 0);
            acc[1][0] = __builtin_amdgcn_mfma_f32_16x16x32_f16(Af[1][kt], b0, acc[1][0], 0, 0, 0);
        }
        // nf1: B from registers
        #pragma unroll
        for (int kt = 0; kt < 16; ++kt) {
            acc[0][1] = __builtin_amdgcn_mfma_f32_16x16x32_f16(Af[0][kt], bn[kt], acc[0][1], 0, 0, 0);
            acc[1][1] = __builtin_amdgcn_mfma_f32_16x16x32_f16(Af[1][kt], bn[kt], acc[1][1], 0, 0, 0);
        }

        // C/D: col = lane&15 (kv col), row = quad*4 + j (q row). Scale already
        // folded into A -> fold exp directly.
        #pragma unroll
        for (int m = 0; m < 2; ++m)
            #pragma unroll
            for (int nf = 0; nf < 2; ++nf)
                #pragma unroll
                for (int j = 0; j < 4; ++j)
                    lacc[m][j] += __expf(acc[m][nf][j]);

        buf ^= 1;
    }

    // reduce over the 16 columns held across l15 lanes
    #pragma unroll
    for (int m = 0; m < 2; ++m)
        #pragma unroll
        for (int j = 0; j < 4; ++j) {
            float v = lacc[m][j];
            v += __shfl_xor(v, 1, 64);
            v += __shfl_xor(v, 2, 64);
            v += __shfl_xor(v, 4, 64);
            v += __shfl_xor(v, 8, 64);
            if (l15 == 0)
                partial[(size_t)cs * NROWS + b * NN + row0 + m * 16 + quad * 4 + j] = v;
        }
}

// ---- kernel 3: out = exp(diag*s) / sum_cs partial
__launch_bounds__(256)
__global__ void finalize_kernel(const float* __restrict__ partial,
                                const float* __restrict__ diag,
                                float* __restrict__ out) {
    const int idx = blockIdx.x * 256 + threadIdx.x;
    float l = partial[idx] + partial[NROWS + idx] +
              partial[2 * NROWS + idx] + partial[3 * NROWS + idx];
    out[idx] = __expf(diag[idx] * SCALE) / l;
}

extern "C" void kernel_launch(void* const* d_in, const int* in_sizes, int n_in,
                              void* d_out, int out_size, void* d_ws, size_t ws_size,
                              hipStream_t stream) {
    const float* q  = (const float*)d_in[0];
    const float* kv = (const float*)d_in[1];
    float* out = (float*)d_out;

    // ws: kvp fp16 packed [16MB] | partial f32[4][16384] (256KB) | diag f32[16384]
    _Float16* kvp   = (_Float16*)d_ws;
    float* partial  = (float*)((char*)d_ws + (size_t)NROWS * ND * 2);
    float* diag     = partial + 4 * NROWS;

    convert_kernel<<<512, 256, 0, stream>>>(q, kv, kvp, diag);
    lse_partial_kernel<<<dim3(16, 32), 256, 0, stream>>>(q, kvp, partial);
    finalize_kernel<<<NROWS / 256, 256, 0, stream>>>(partial, diag, out);
}

// Round 6
// 187.477 us; speedup vs baseline: 1.2823x; 1.1189x over previous
//
#include <hip/hip_runtime.h>
#include <hip/hip_fp16.h>

// dot_attention: out[b,n] = exp(diag*s - lse_n), s = (D/2)^-0.5 = 1/16.
// B=4, N=4096, D=512. Inputs fp32, output fp32.
// No fp32 MFMA on CDNA4 -> fp16 convert + mfma_f32_16x16x32_f16.
//
// R6 changes vs R5:
//  1. convert: no q read, no diag dot (diag extracted from MFMA acc in lse).
//     LDS-transposed packing -> coalesced global read AND write. 80 MB traffic.
//  2. lse: STAGE DMA issued BEFORE bn register loads (+sched_barrier pin) so
//     the next barrier's vmcnt(0) target is at the HEAD of the vector queue,
//     not behind 128 KB of bn traffic (R5's regression).
//  3. diag: at the iter where kv-group == wave's q-rows, acc[m][m] holds the
//     scaled diagonal scores; 16 lanes/wave extract and store them.

typedef _Float16 f16x8 __attribute__((ext_vector_type(8)));  // MFMA A/B frag (4 VGPR)
typedef float    f32x4 __attribute__((ext_vector_type(4)));  // MFMA C/D frag

#define NB 4
#define NN 4096
#define ND 512
#define SCALE 0.0625f
#define NROWS (NB * NN)            // 16384
#define FRAG_B 1024                // bytes per packed fragment
#define GRP_B  16384               // bytes per 16-row group (16 frags)
#define CPITCH 520                 // convert LDS row pitch (halfwords) = 1040 B

__device__ __forceinline__ void gld16(const void* g, void* l) {
    __builtin_amdgcn_global_load_lds(
        (const __attribute__((address_space(1))) unsigned int*)g,
        (__attribute__((address_space(3))) unsigned int*)l, 16, 0, 0);
}

__device__ __forceinline__ f16x8 cvt8(float4 a, float4 b) {
    f16x8 r;
    r[0] = (_Float16)a.x; r[1] = (_Float16)a.y; r[2] = (_Float16)a.z; r[3] = (_Float16)a.w;
    r[4] = (_Float16)b.x; r[5] = (_Float16)b.y; r[6] = (_Float16)b.z; r[7] = (_Float16)b.w;
    return r;
}

__device__ __forceinline__ f16x8 cvt8s(float4 a, float4 b, float s) {
    f16x8 r;
    r[0] = (_Float16)(a.x * s); r[1] = (_Float16)(a.y * s);
    r[2] = (_Float16)(a.z * s); r[3] = (_Float16)(a.w * s);
    r[4] = (_Float16)(b.x * s); r[5] = (_Float16)(b.y * s);
    r[6] = (_Float16)(b.z * s); r[7] = (_Float16)(b.w * s);
    return r;
}

// ---- kernel 1: kv fp32 -> fp16, packed in B-frag order via LDS transpose.
// One 16-row group per block (1024 blocks, 4/CU). Reads coalesced rows,
// writes coalesced 1KB frags. frag(g,kt) byte lane*16 = kv[g*16 + (lane&15)]
// [kt*32 + (lane>>4)*8 ..+8) as fp16.
__launch_bounds__(256)
__global__ void convert_kernel(const float* __restrict__ kv,
                               _Float16* __restrict__ kvp) {
    __shared__ _Float16 s[16 * CPITCH];
    const int g    = blockIdx.x;
    const int tid  = threadIdx.x;
    const int wid  = tid >> 6;
    const int lane = tid & 63;
    const int l15  = lane & 15;
    const int quad = lane >> 4;

    #pragma unroll
    for (int i = 0; i < 4; ++i) {
        const int r = wid * 4 + i;
        const float* src = kv + ((size_t)g * 16 + r) * ND + lane * 8;
        float4 a = *(const float4*)src;
        float4 b = *(const float4*)(src + 4);
        *(f16x8*)(s + r * CPITCH + lane * 8) = cvt8(a, b);
    }
    __syncthreads();

    _Float16* dst = kvp + (size_t)g * 8192 + lane * 8;
    #pragma unroll
    for (int p = 0; p < 4; ++p) {
        const int kt = wid * 4 + p;
        f16x8 v = *(const f16x8*)(s + l15 * CPITCH + kt * 32 + quad * 8);
        *(f16x8*)(dst + kt * 512) = v;
    }
}

// ---- kernel 2: per-row sum of exp(score) over a 1024-column split + diag.
// grid (16: b*4+cs, 32: rowblock) = 512 blocks, 256 threads = 4 waves,
// 2 blocks/CU, 2 waves/SIMD. Wave: 32 q-rows (Af 128 regs), per iter 32 kv
// rows: even group via LDS DMA (dbuf), odd group via coalesced global b128.
__launch_bounds__(256, 2)
__global__ void lse_partial_kernel(const float* __restrict__ q,
                                   const _Float16* __restrict__ kvp,
                                   float* __restrict__ partial,
                                   float* __restrict__ diagsc) {
    __shared__ char sbuf[2][GRP_B];

    const int bc = blockIdx.x;          // b*4 + cs (fastest -> spread over XCDs)
    const int b  = bc >> 2;
    const int cs = bc & 3;
    const int rb = blockIdx.y;
    const int tid  = threadIdx.x;
    const int wid  = tid >> 6;
    const int lane = tid & 63;
    const int l15  = lane & 15;
    const int quad = lane >> 4;

    const int row0 = rb * 128 + wid * 32;    // wave's first q-row (in batch)
    // iteration whose 32-col kv group coincides with this wave's 32 q-rows
    const int it_diag = ((row0 >> 10) == cs) ? ((row0 - cs * 1024) >> 5) : -1;

    // ---- A fragments: q fp32 -> fp16 scaled by 1/16 (exact pow2).
    f16x8 Af[2][16];
    #pragma unroll
    for (int m = 0; m < 2; ++m) {
        const float* qrow = q + ((size_t)(b * NN + row0 + m * 16 + l15)) * ND + quad * 8;
        #pragma unroll
        for (int k = 0; k < 16; ++k) {
            float4 u0 = *(const float4*)(qrow + k * 32);
            float4 u1 = *(const float4*)(qrow + k * 32 + 4);
            Af[m][k] = cvt8s(u0, u1, SCALE);
        }
    }

    float lacc[2][4];
    #pragma unroll
    for (int m = 0; m < 2; ++m)
        #pragma unroll
        for (int j = 0; j < 4; ++j)
            lacc[m][j] = 0.f;

    // packed base for this (b,cs): groups [b*256 + cs*64, +64)
    const char* pb  = (const char*)kvp + ((size_t)(b * 256 + cs * 64)) * GRP_B;
    const char* g1b = pb + GRP_B + (size_t)lane * 16;   // odd group, lane chunk
    const char* ssb = pb + (size_t)lane * 16;           // even group, lane chunk

    // stage even group of tile `it_` into sbuf[buf_]: 4 frag-DMAs per wave
    #define STAGE(it_, buf_)                                                  \
        do {                                                                  \
            const char* sp_ = ssb + (size_t)(it_) * (2 * GRP_B);              \
            char* lb_ = sbuf[buf_];                                           \
            _Pragma("unroll")                                                 \
            for (int p_ = 0; p_ < 4; ++p_) {                                  \
                int kt_ = wid * 4 + p_;                                       \
                gld16(sp_ + kt_ * FRAG_B, lb_ + kt_ * FRAG_B);                \
            }                                                                 \
        } while (0)

    STAGE(0, 0);
    int buf = 0;

    for (int it = 0; it < 32; ++it) {
        __syncthreads();                      // tile-`it` DMA drained

        // DMA for iter+1 FIRST: keeps it at the head of the vmcnt queue so
        // the next barrier's vmcnt(0) has nothing left to drain (R5 lesson).
        if (it + 1 < 32) STAGE(it + 1, buf ^ 1);
        __builtin_amdgcn_sched_barrier(0);    // don't hoist bn loads above DMA

        // coalesced register loads of the odd group's 16 frags (L1/L2-hot)
        f16x8 bn[16];
        {
            const char* g1 = g1b + (size_t)it * (2 * GRP_B);
            #pragma unroll
            for (int kt = 0; kt < 16; ++kt)
                bn[kt] = *(const f16x8*)(g1 + kt * FRAG_B);
        }

        const char* lb = sbuf[buf] + (size_t)lane * 16;
        f32x4 acc[2][2];
        #pragma unroll
        for (int m = 0; m < 2; ++m)
            #pragma unroll
            for (int nf = 0; nf < 2; ++nf)
                acc[m][nf] = (f32x4){0.f, 0.f, 0.f, 0.f};

        // nf0: B from LDS (covers bn[] load latency)
        #pragma unroll
        for (int kt = 0; kt < 16; ++kt) {
            f16x8 b0 = *(const f16x8*)(lb + kt * FRAG_B);
            acc[0][0] = __builtin_amdgcn_mfma_f32_16x16x32_f16(Af[0][kt], b0, acc[0][0], 0, 0, 0);
            acc[1][0] = __builtin_amdgcn_mfma_f32_16x16x32_f16(Af[1][kt], b0, acc[1][0], 0, 0, 0);
        }
        // nf1: B from registers
        #pragma unroll
        for (int kt = 0; kt < 16; ++kt) {
            acc[0][1] = __builtin_amdgcn_mfma_f32_16x16x32_f16(Af[0][kt], bn[kt], acc[0][1], 0, 0, 0);
            acc[1][1] = __builtin_amdgcn_mfma_f32_16x16x32_f16(Af[1][kt], bn[kt], acc[1][1], 0, 0, 0);
        }

        // diag extraction: C/D row = quad*4+j, col = nf*16+l15. On the
        // aligned iter, row==col  =>  nf==m, l15==quad*4+j.
        if (it == it_diag) {
            if ((l15 >> 2) == quad) {
                const int j = l15 & 3;
                float d0 = (j == 0) ? acc[0][0][0] : (j == 1) ? acc[0][0][1]
                         : (j == 2) ? acc[0][0][2] : acc[0][0][3];
                float d1 = (j == 0) ? acc[1][1][0] : (j == 1) ? acc[1][1][1]
                         : (j == 2) ? acc[1][1][2] : acc[1][1][3];
                diagsc[b * NN + row0 + l15]      = d0;
                diagsc[b * NN + row0 + 16 + l15] = d1;
            }
        }

        // scale folded into A -> acc IS the scaled score; fold exp.
        #pragma unroll
        for (int m = 0; m < 2; ++m)
            #pragma unroll
            for (int nf = 0; nf < 2; ++nf)
                #pragma unroll
                for (int j = 0; j < 4; ++j)
                    lacc[m][j] += __expf(acc[m][nf][j]);

        buf ^= 1;
    }

    // reduce over the 16 columns held across l15 lanes
    #pragma unroll
    for (int m = 0; m < 2; ++m)
        #pragma unroll
        for (int j = 0; j < 4; ++j) {
            float v = lacc[m][j];
            v += __shfl_xor(v, 1, 64);
            v += __shfl_xor(v, 2, 64);
            v += __shfl_xor(v, 4, 64);
            v += __shfl_xor(v, 8, 64);
            if (l15 == 0)
                partial[(size_t)cs * NROWS + b * NN + row0 + m * 16 + quad * 4 + j] = v;
        }
}

// ---- kernel 3: out = exp(diag_scaled) / sum_cs partial
__launch_bounds__(256)
__global__ void finalize_kernel(const float* __restrict__ partial,
                                const float* __restrict__ diagsc,
                                float* __restrict__ out) {
    const int idx = blockIdx.x * 256 + threadIdx.x;
    float l = partial[idx] + partial[NROWS + idx] +
              partial[2 * NROWS + idx] + partial[3 * NROWS + idx];
    out[idx] = __expf(diagsc[idx]) / l;
}

extern "C" void kernel_launch(void* const* d_in, const int* in_sizes, int n_in,
                              void* d_out, int out_size, void* d_ws, size_t ws_size,
                              hipStream_t stream) {
    const float* q  = (const float*)d_in[0];
    const float* kv = (const float*)d_in[1];
    float* out = (float*)d_out;

    // ws: kvp fp16 packed [16MB] | partial f32[4][16384] | diagsc f32[16384]
    _Float16* kvp   = (_Float16*)d_ws;
    float* partial  = (float*)((char*)d_ws + (size_t)NROWS * ND * 2);
    float* diagsc   = partial + 4 * NROWS;

    convert_kernel<<<1024, 256, 0, stream>>>(kv, kvp);
    lse_partial_kernel<<<dim3(16, 32), 256, 0, stream>>>(q, kvp, partial, diagsc);
    finalize_kernel<<<NROWS / 256, 256, 0, stream>>>(partial, diagsc, out);
}

// Round 7
// 161.421 us; speedup vs baseline: 1.4892x; 1.1614x over previous
//
#include <hip/hip_runtime.h>
#include <hip/hip_fp16.h>

// dot_attention: out[b,n] = exp(diag*s - lse_n), s = (D/2)^-0.5 = 1/16.
// B=4, N=4096, D=512. Inputs fp32, output fp32.
// No fp32 MFMA on CDNA4 -> fp16 convert + mfma_f32_16x16x32_f16.
//
// R7: pure-LDS B path (R3 structure) + packed conflict-free layout (R5).
//  - R5/R6's split-source B regressed: bn direct loads share the same L1/TA
//    path as the DMA (~64 B/cyc/CU) -> 160 KB/CU-iter vs 64 KB pure-LDS.
//  - Packed layout measured 0 bank conflicts (R5) vs +4 cyc/read in R3.
//  - No sched_barrier (R6 regression; m141).
//  - A-frags pre-scaled by s*log2(e): exp(score) == v_exp_f32(acc), no mul.
// Model per CU-iter-pair: LDS 256KB@128B/cyc=2048c, DMA 64KB=1024c,
// MFMA 128x19.4=2483c -> MFMA-bound.

typedef _Float16 f16x8 __attribute__((ext_vector_type(8)));  // MFMA A/B frag (4 VGPR)
typedef float    f32x4 __attribute__((ext_vector_type(4)));  // MFMA C/D frag

#define NB 4
#define NN 4096
#define ND 512
#define SCALE 0.0625f
#define LOG2E 1.4426950408889634f
#define NROWS (NB * NN)            // 16384
#define FRAG_B 1024                // bytes per packed fragment
#define GRP_B  16384               // bytes per 16-row group (16 frags)
#define TILE_B 32768               // 32-row tile = 2 groups
#define CPITCH 520                 // convert LDS row pitch (halfwords) = 1040 B

__device__ __forceinline__ void gld16(const void* g, void* l) {
    __builtin_amdgcn_global_load_lds(
        (const __attribute__((address_space(1))) unsigned int*)g,
        (__attribute__((address_space(3))) unsigned int*)l, 16, 0, 0);
}

__device__ __forceinline__ f16x8 cvt8(float4 a, float4 b) {
    f16x8 r;
    r[0] = (_Float16)a.x; r[1] = (_Float16)a.y; r[2] = (_Float16)a.z; r[3] = (_Float16)a.w;
    r[4] = (_Float16)b.x; r[5] = (_Float16)b.y; r[6] = (_Float16)b.z; r[7] = (_Float16)b.w;
    return r;
}

__device__ __forceinline__ f16x8 cvt8s(float4 a, float4 b, float s) {
    f16x8 r;
    r[0] = (_Float16)(a.x * s); r[1] = (_Float16)(a.y * s);
    r[2] = (_Float16)(a.z * s); r[3] = (_Float16)(a.w * s);
    r[4] = (_Float16)(b.x * s); r[5] = (_Float16)(b.y * s);
    r[6] = (_Float16)(b.z * s); r[7] = (_Float16)(b.w * s);
    return r;
}

// ---- kernel 1: kv fp32 -> fp16, packed in B-frag order via LDS transpose.
// One 16-row group per block (1024 blocks). Reads coalesced rows, writes
// coalesced 1KB frags. frag(g,kt) byte lane*16 = kv[g*16 + (lane&15)]
// [kt*32 + (lane>>4)*8 ..+8) as fp16.
__launch_bounds__(256)
__global__ void convert_kernel(const float* __restrict__ kv,
                               _Float16* __restrict__ kvp) {
    __shared__ _Float16 s[16 * CPITCH];
    const int g    = blockIdx.x;
    const int tid  = threadIdx.x;
    const int wid  = tid >> 6;
    const int lane = tid & 63;
    const int l15  = lane & 15;
    const int quad = lane >> 4;

    #pragma unroll
    for (int i = 0; i < 4; ++i) {
        const int r = wid * 4 + i;
        const float* src = kv + ((size_t)g * 16 + r) * ND + lane * 8;
        float4 a = *(const float4*)src;
        float4 b = *(const float4*)(src + 4);
        *(f16x8*)(s + r * CPITCH + lane * 8) = cvt8(a, b);
    }
    __syncthreads();

    _Float16* dst = kvp + (size_t)g * 8192 + lane * 8;
    #pragma unroll
    for (int p = 0; p < 4; ++p) {
        const int kt = wid * 4 + p;
        f16x8 v = *(const f16x8*)(s + l15 * CPITCH + kt * 32 + quad * 8);
        *(f16x8*)(dst + kt * 512) = v;
    }
}

// ---- kernel 2: per-row sum of exp(score) over a 1024-column split + diag.
// grid (16: b*4+cs, 32: rowblock) = 512 blocks, 256 threads = 4 waves,
// 2 blocks/CU (2x32KB LDS dbuf), 2 waves/SIMD. Wave: 32 q-rows (Af 128
// regs). Per iter: one 32-row kv tile (2 packed groups), all via LDS DMA.
__launch_bounds__(256, 2)
__global__ void lse_partial_kernel(const float* __restrict__ q,
                                   const _Float16* __restrict__ kvp,
                                   float* __restrict__ partial,
                                   float* __restrict__ diagsc) {
    __shared__ char sbuf[2][TILE_B];

    const int bc = blockIdx.x;          // b*4 + cs (fastest -> spread over XCDs)
    const int b  = bc >> 2;
    const int cs = bc & 3;
    const int rb = blockIdx.y;
    const int tid  = threadIdx.x;
    const int wid  = tid >> 6;
    const int lane = tid & 63;
    const int l15  = lane & 15;
    const int quad = lane >> 4;

    const int row0 = rb * 128 + wid * 32;    // wave's first q-row (in batch)
    // iteration whose 32-col kv tile coincides with this wave's 32 q-rows
    const int it_diag = ((row0 >> 10) == cs) ? ((row0 - cs * 1024) >> 5) : -1;

    // ---- A fragments: q fp32 -> fp16 scaled by s*log2e (exp2 path).
    f16x8 Af[2][16];
    #pragma unroll
    for (int m = 0; m < 2; ++m) {
        const float* qrow = q + ((size_t)(b * NN + row0 + m * 16 + l15)) * ND + quad * 8;
        #pragma unroll
        for (int k = 0; k < 16; ++k) {
            float4 u0 = *(const float4*)(qrow + k * 32);
            float4 u1 = *(const float4*)(qrow + k * 32 + 4);
            Af[m][k] = cvt8s(u0, u1, SCALE * LOG2E);
        }
    }

    float lacc[2][4];
    #pragma unroll
    for (int m = 0; m < 2; ++m)
        #pragma unroll
        for (int j = 0; j < 4; ++j)
            lacc[m][j] = 0.f;

    // packed base for this (b,cs): groups [b*256 + cs*64, +64) = 32 tiles
    const char* pb  = (const char*)kvp + ((size_t)(b * 256 + cs * 64)) * GRP_B;
    const char* ssb = pb + (size_t)lane * 16;

    // stage 32-frag tile `it_` into sbuf[buf_]: 8 frag-DMAs per wave
    #define STAGE(it_, buf_)                                                  \
        do {                                                                  \
            const char* sp_ = ssb + (size_t)(it_) * TILE_B;                   \
            char* lb_ = sbuf[buf_];                                           \
            _Pragma("unroll")                                                 \
            for (int p_ = 0; p_ < 8; ++p_) {                                  \
                int f_ = wid * 8 + p_;                                        \
                gld16(sp_ + f_ * FRAG_B, lb_ + f_ * FRAG_B);                  \
            }                                                                 \
        } while (0)

    STAGE(0, 0);
    int buf = 0;

    for (int it = 0; it < 32; ++it) {
        __syncthreads();                      // tile-`it` DMA drained
        if (it + 1 < 32) STAGE(it + 1, buf ^ 1);

        const char* lb = sbuf[buf] + (size_t)lane * 16;
        f32x4 acc[2][2];
        #pragma unroll
        for (int m = 0; m < 2; ++m)
            #pragma unroll
            for (int nf = 0; nf < 2; ++nf)
                acc[m][nf] = (f32x4){0.f, 0.f, 0.f, 0.f};

        #pragma unroll
        for (int kt = 0; kt < 16; ++kt) {
            f16x8 b0 = *(const f16x8*)(lb + kt * FRAG_B);
            f16x8 b1 = *(const f16x8*)(lb + GRP_B + kt * FRAG_B);
            acc[0][0] = __builtin_amdgcn_mfma_f32_16x16x32_f16(Af[0][kt], b0, acc[0][0], 0, 0, 0);
            acc[1][0] = __builtin_amdgcn_mfma_f32_16x16x32_f16(Af[1][kt], b0, acc[1][0], 0, 0, 0);
            acc[0][1] = __builtin_amdgcn_mfma_f32_16x16x32_f16(Af[0][kt], b1, acc[0][1], 0, 0, 0);
            acc[1][1] = __builtin_amdgcn_mfma_f32_16x16x32_f16(Af[1][kt], b1, acc[1][1], 0, 0, 0);
        }

        // diag extraction: C/D row = quad*4+j, col = nf*16+l15. On the
        // aligned iter, row==col  =>  nf==m, l15==quad*4+j.
        if (it == it_diag) {
            if ((l15 >> 2) == quad) {
                const int j = l15 & 3;
                float d0 = (j == 0) ? acc[0][0][0] : (j == 1) ? acc[0][0][1]
                         : (j == 2) ? acc[0][0][2] : acc[0][0][3];
                float d1 = (j == 0) ? acc[1][1][0] : (j == 1) ? acc[1][1][1]
                         : (j == 2) ? acc[1][1][2] : acc[1][1][3];
                diagsc[b * NN + row0 + l15]      = d0;   // score*log2e
                diagsc[b * NN + row0 + 16 + l15] = d1;
            }
        }

        // acc = score*log2e -> exp(score) = exp2(acc) = native v_exp_f32
        #pragma unroll
        for (int m = 0; m < 2; ++m)
            #pragma unroll
            for (int nf = 0; nf < 2; ++nf)
                #pragma unroll
                for (int j = 0; j < 4; ++j)
                    lacc[m][j] += __builtin_amdgcn_exp2f(acc[m][nf][j]);

        buf ^= 1;
    }

    // reduce over the 16 columns held across l15 lanes
    #pragma unroll
    for (int m = 0; m < 2; ++m)
        #pragma unroll
        for (int j = 0; j < 4; ++j) {
            float v = lacc[m][j];
            v += __shfl_xor(v, 1, 64);
            v += __shfl_xor(v, 2, 64);
            v += __shfl_xor(v, 4, 64);
            v += __shfl_xor(v, 8, 64);
            if (l15 == 0)
                partial[(size_t)cs * NROWS + b * NN + row0 + m * 16 + quad * 4 + j] = v;
        }
}

// ---- kernel 3: out = exp2(diag_scaled) / sum_cs partial
__launch_bounds__(256)
__global__ void finalize_kernel(const float* __restrict__ partial,
                                const float* __restrict__ diagsc,
                                float* __restrict__ out) {
    const int idx = blockIdx.x * 256 + threadIdx.x;
    float l = partial[idx] + partial[NROWS + idx] +
              partial[2 * NROWS + idx] + partial[3 * NROWS + idx];
    out[idx] = exp2f(diagsc[idx]) / l;
}

extern "C" void kernel_launch(void* const* d_in, const int* in_sizes, int n_in,
                              void* d_out, int out_size, void* d_ws, size_t ws_size,
                              hipStream_t stream) {
    const float* q  = (const float*)d_in[0];
    const float* kv = (const float*)d_in[1];
    float* out = (float*)d_out;

    // ws: kvp fp16 packed [16MB] | partial f32[4][16384] | diagsc f32[16384]
    _Float16* kvp   = (_Float16*)d_ws;
    float* partial  = (float*)((char*)d_ws + (size_t)NROWS * ND * 2);
    float* diagsc   = partial + 4 * NROWS;

    convert_kernel<<<1024, 256, 0, stream>>>(kv, kvp);
    lse_partial_kernel<<<dim3(16, 32), 256, 0, stream>>>(q, kvp, partial, diagsc);
    finalize_kernel<<<NROWS / 256, 256, 0, stream>>>(partial, diagsc, out);
}